// Round 6
// baseline (459.754 us; speedup 1.0000x reference)
//
#include <hip/hip_runtime.h>

#define B_ 2
#define T_ 2048
#define D_ 2048
#define N_ 16
#define H_ 128
constexpr int WIN = 1024;

typedef __attribute__((ext_vector_type(8))) short s16x8;
typedef __attribute__((ext_vector_type(4))) float f32x4;
typedef __attribute__((ext_vector_type(4))) unsigned short u16x4;

typedef const __attribute__((address_space(1))) void cglobal_void;
typedef __attribute__((address_space(3))) void lds_void;

__device__ __forceinline__ unsigned short f2b(float f) {
  union { float f; unsigned u; } v; v.f = f;
  unsigned r = v.u + 0x7FFFu + ((v.u >> 16) & 1u);
  return (unsigned short)(r >> 16);
}
__device__ __forceinline__ float b2f(unsigned short u) {
  union { unsigned u; float f; } v; v.u = ((unsigned)u) << 16;
  return v.f;
}

// ---------------------------------------------------------------------------
// Dtype detector (fp32 vs bf16 inputs): fp32 mantissa halves look like big
// exponents ~40% of the time; bf16 activations never.
// ---------------------------------------------------------------------------
__global__ __launch_bounds__(256) void detect_kernel(
    const unsigned short* __restrict__ x, int* __restrict__ flag) {
  __shared__ int cnt[256];
  const int tid = threadIdx.x;
  int c = 0;
  for (int i = tid; i < 4096; i += 256) {
    const unsigned short u = x[2 * i];
    const int e = (u >> 7) & 0xFF;
    if (e >= 154) ++c;
  }
  cnt[tid] = c;
  __syncthreads();
  for (int s = 128; s > 0; s >>= 1) {
    if (tid < s) cnt[tid] += cnt[tid + s];
    __syncthreads();
  }
  if (tid == 0) *flag = cnt[0];
}

// x -> canonical bf16, 4 elems/thread
__global__ __launch_bounds__(256) void convert_x_kernel(
    const void* __restrict__ src, unsigned short* __restrict__ dst,
    const int* __restrict__ flag, int n4) {
  const int i = blockIdx.x * 256 + threadIdx.x;
  if (i >= n4) return;
  const bool isf = (*flag > 64);
  u16x4 o;
  if (isf) {
    const float4 f = ((const float4*)src)[i];
    o[0] = f2b(f.x); o[1] = f2b(f.y); o[2] = f2b(f.z); o[3] = f2b(f.w);
  } else {
    o = ((const u16x4*)src)[i];
  }
  *(u16x4*)(dst + 4 * (size_t)i) = o;
}

// ---------------------------------------------------------------------------
// Batched tiled transpose, dtype-adaptive input, bf16 out.
// ---------------------------------------------------------------------------
__global__ __launch_bounds__(256) void transpose_kernel(
    const void* __restrict__ src, unsigned short* __restrict__ dst,
    int R, int C, const int* __restrict__ flag) {
  __shared__ unsigned short tile[32][33];
  const bool isf = (*flag > 64);
  const int c0 = blockIdx.x * 32, r0 = blockIdx.y * 32;
  const size_t base = (size_t)blockIdx.z * R * C;
  const int tx = threadIdx.x, ty = threadIdx.y;
#pragma unroll
  for (int j = 0; j < 32; j += 8) {
    const size_t idx = base + (size_t)(r0 + ty + j) * C + c0 + tx;
    tile[ty + j][tx] = isf ? f2b(((const float*)src)[idx])
                           : ((const unsigned short*)src)[idx];
  }
  __syncthreads();
#pragma unroll
  for (int j = 0; j < 32; j += 8)
    dst[base + (size_t)(c0 + ty + j) * R + r0 + tx] = tile[tx][ty + j];
}

// bf16-only batched transpose (V [t][h] -> [h][t] per (b,n))
__global__ __launch_bounds__(256) void transpose_bf16_kernel(
    const unsigned short* __restrict__ src, unsigned short* __restrict__ dst,
    int R, int C) {
  __shared__ unsigned short tile[32][33];
  const int c0 = blockIdx.x * 32, r0 = blockIdx.y * 32;
  const size_t base = (size_t)blockIdx.z * R * C;
  const int tx = threadIdx.x, ty = threadIdx.y;
#pragma unroll
  for (int j = 0; j < 32; j += 8)
    tile[ty + j][tx] = src[base + (size_t)(r0 + ty + j) * C + c0 + tx];
  __syncthreads();
#pragma unroll
  for (int j = 0; j < 32; j += 8)
    dst[base + (size_t)(c0 + ty + j) * R + r0 + tx] = tile[tx][ty + j];
}

// ---------------------------------------------------------------------------
// 128x128-tile bf16 GEMM, K=2048, BK=64, xor-swizzled LDS (conflict-free,
// verified SQ_LDS_BANK_CONFLICT=0). mode 0: final projection (fp32/bf16 per
// flag). mode 1: qkv scatter [s][b][n][t][h].
// ---------------------------------------------------------------------------
__global__ __launch_bounds__(256) void gemm128_kernel(
    const unsigned short* __restrict__ A,
    const unsigned short* __restrict__ Bt,
    void* __restrict__ outp,
    int mode, const int* __restrict__ flag) {
  constexpr int K = D_;
  __shared__ unsigned short As[128 * 64];
  __shared__ unsigned short Bs[128 * 64];
  const int tid = threadIdx.x;
  const int lane = tid & 63;
  const int lr = lane & 15, lq = lane >> 4;
  const int wave = tid >> 6;
  const int wm = (wave >> 1) * 64, wn = (wave & 1) * 64;
  const size_t m0 = (size_t)blockIdx.x * 128;
  const unsigned short* pA = A + m0 * K;
  const unsigned short* pB = Bt + (size_t)blockIdx.y * 128 * K;

  f32x4 acc[4][4] = {};

  const int cg = (tid & 7) ^ ((tid >> 3) & 7);
  size_t goff[4];
#pragma unroll
  for (int j = 0; j < 4; ++j)
    goff[j] = (size_t)(j * 32 + (tid >> 3)) * K + cg * 8;

  for (int k0 = 0; k0 < K; k0 += 64) {
    __syncthreads();
#pragma unroll
    for (int j = 0; j < 4; ++j) {
      __builtin_amdgcn_global_load_lds((cglobal_void*)(pA + goff[j] + k0),
                                       (lds_void*)(As + (size_t)(j * 256 + tid) * 8), 16, 0, 0);
      __builtin_amdgcn_global_load_lds((cglobal_void*)(pB + goff[j] + k0),
                                       (lds_void*)(Bs + (size_t)(j * 256 + tid) * 8), 16, 0, 0);
    }
    __syncthreads();
#pragma unroll
    for (int kq = 0; kq < 2; ++kq) {
      const int co = (((kq << 2) + lq) ^ (lr & 7)) * 8;
      s16x8 af[4], bfr[4];
#pragma unroll
      for (int mb = 0; mb < 4; ++mb)
        af[mb] = *(const s16x8*)(As + (wm + mb * 16 + lr) * 64 + co);
#pragma unroll
      for (int nb = 0; nb < 4; ++nb)
        bfr[nb] = *(const s16x8*)(Bs + (wn + nb * 16 + lr) * 64 + co);
#pragma unroll
      for (int mb = 0; mb < 4; ++mb)
#pragma unroll
        for (int nb = 0; nb < 4; ++nb)
          acc[mb][nb] = __builtin_amdgcn_mfma_f32_16x16x32_bf16(af[mb], bfr[nb], acc[mb][nb], 0, 0, 0);
    }
  }

  if (mode == 0) {
    const bool isf = (*flag > 64);
#pragma unroll
    for (int mb = 0; mb < 4; ++mb) {
      const size_t r = m0 + wm + mb * 16 + lq * 4;
#pragma unroll
      for (int nb = 0; nb < 4; ++nb) {
        const size_t c = (size_t)blockIdx.y * 128 + wn + nb * 16 + lr;
#pragma unroll
        for (int i = 0; i < 4; ++i) {
          if (isf) ((float*)outp)[(r + i) * D_ + c] = acc[mb][nb][i];
          else ((unsigned short*)outp)[(r + i) * D_ + c] = f2b(acc[mb][nb][i]);
        }
      }
    }
  } else {
    unsigned short* op = (unsigned short*)outp;
    const int s = blockIdx.y >> 4, n = blockIdx.y & 15;
    const size_t SB = (size_t)B_ * N_ * T_ * H_;
#pragma unroll
    for (int mb = 0; mb < 4; ++mb) {
#pragma unroll
      for (int i = 0; i < 4; ++i) {
        const size_t r = m0 + wm + mb * 16 + lq * 4 + i;
        const int b = (int)(r >> 11);
        const int t = (int)(r & 2047);
        const size_t base = s * SB + (size_t)(b * N_ + n) * T_ * H_ + (size_t)t * H_;
#pragma unroll
        for (int nb = 0; nb < 4; ++nb)
          op[base + wn + nb * 16 + lr] = f2b(acc[mb][nb][i]);
      }
    }
  }
}

// ---------------------------------------------------------------------------
// RoPE in place on K rows only (Q rope is fused into attn's frag load).
// One wave per 128-elem row.
// ---------------------------------------------------------------------------
__global__ __launch_bounds__(256) void rope_kernel(unsigned short* __restrict__ k) {
  const int tid = threadIdx.x;
  const int lane = tid & 63;
  const size_t row = (size_t)blockIdx.x * 4 + (tid >> 6);  // B*N*T rows
  const int t = (int)(row & (T_ - 1));
  unsigned short* p = k + row * H_;
  float x1 = b2f(p[lane]), x2 = b2f(p[lane + 64]);
  const float inv_ts = exp2f(-0.20762050f * (float)lane);  // 10000^(-lane/64)
  float sv, cv;
  __sincosf((float)t * inv_ts, &sv, &cv);
  p[lane] = f2b(x1 * cv - x2 * sv);
  p[lane + 64] = f2b(x2 * cv + x1 * sv);
}

// ---------------------------------------------------------------------------
// Flash attention, Q-tile 128 (wave = 32 queries as 2 m-blocks), key tiles 64.
// Q-RoPE + H^-0.5 scale fused in-register at frag load (pair of element
// (kc,j) is (kc+2,j) in the SAME lane for the 16x16x32 A-layout).
// Fixed-offset softmax (softcap bounds logits); l deferred to epilogue.
// K/V staged via global_load_lds into xor-swizzled LDS; Ps aliases Ks.
// ---------------------------------------------------------------------------
__global__ __launch_bounds__(256, 2) void attn_kernel(
    const unsigned short* __restrict__ qkv,
    const unsigned short* __restrict__ vt,
    unsigned short* __restrict__ enc) {
  const int tid = threadIdx.x, lane = tid & 63, wave = tid >> 6;
  const int lr = lane & 15, lq = lane >> 4;
  const int bn = blockIdx.x;
  const int b = bn >> 4, n = bn & 15;
  const int t0 = blockIdx.y * 128;
  const size_t SB = (size_t)B_ * N_ * T_ * H_;
  const unsigned short* qp = qkv + (size_t)bn * T_ * H_;
  const unsigned short* kp = qp + SB;
  const unsigned short* vp = vt + (size_t)bn * T_ * H_;  // [h][t]

  __shared__ unsigned short Ks[64 * 128];  // [key][h], swizzled; Ps aliases
  __shared__ unsigned short Vt[128 * 64];  // [h][key], swizzled
  unsigned short* Ps = Ks + wave * 2048;   // per-wave 32 rows x 64

  // staging offsets
  const int cgK = (tid & 15) ^ ((tid >> 4) & 15);
  const int cgV = (tid & 7) ^ ((tid >> 3) & 7);
  size_t goffK[4], goffV[4];
#pragma unroll
  for (int j = 0; j < 4; ++j) {
    goffK[j] = (size_t)(j * 16 + (tid >> 4)) * H_ + cgK * 8;
    goffV[j] = (size_t)(j * 32 + (tid >> 3)) * T_ + cgV * 8;
  }

  // Q fragments (A-layout) + fused RoPE + scale
  s16x8 aq[2][4];
#pragma unroll
  for (int mb = 0; mb < 2; ++mb) {
    const int t = t0 + wave * 32 + mb * 16 + lr;
#pragma unroll
    for (int kc = 0; kc < 4; ++kc)
      aq[mb][kc] = *(const s16x8*)(qp + (size_t)t * H_ + kc * 32 + lq * 8);
#pragma unroll
    for (int kc = 0; kc < 2; ++kc) {
#pragma unroll
      for (int j = 0; j < 8; ++j) {
        const int i = kc * 32 + lq * 8 + j;  // rope pair index in [0,64)
        const float inv_ts = exp2f(-0.20762050f * (float)i);
        float sv, cv;
        __sincosf((float)t * inv_ts, &sv, &cv);
        const float x1 = b2f((unsigned short)aq[mb][kc][j]);
        const float x2 = b2f((unsigned short)aq[mb][kc + 2][j]);
        aq[mb][kc][j] = (short)f2b((x1 * cv - x2 * sv) * 0.08838834764831845f);
        aq[mb][kc + 2][j] = (short)f2b((x2 * cv + x1 * sv) * 0.08838834764831845f);
      }
    }
  }

  f32x4 oacc[2][8] = {};
  float lp[2][4] = {};

  const int s_lo = (t0 >= 1024) ? (t0 - 1024) : 0;
  constexpr float C_IN = 0.05770780f;     // 2*log2(e)/50
  constexpr float M_SCALE = -144.269504f; // -2*50*log2(e)
  constexpr float M_BIAS = 86.56f;

  for (int s0 = s_lo; s0 <= t0 + 127; s0 += 64) {
    __syncthreads();  // (A) prev-iter Vt/Ps reads done before restage
#pragma unroll
    for (int j = 0; j < 4; ++j) {
      __builtin_amdgcn_global_load_lds((cglobal_void*)(kp + (size_t)s0 * H_ + goffK[j]),
                                       (lds_void*)(Ks + (size_t)(j * 256 + tid) * 8), 16, 0, 0);
      __builtin_amdgcn_global_load_lds((cglobal_void*)(vp + goffV[j] + s0),
                                       (lds_void*)(Vt + (size_t)(j * 256 + tid) * 8), 16, 0, 0);
    }
    __syncthreads();  // (B) staging visible

    // QK^T -> p
    float p[2][4][4];
#pragma unroll
    for (int sb = 0; sb < 4; ++sb) {
      f32x4 a[2] = {};
#pragma unroll
      for (int kc = 0; kc < 4; ++kc) {
        const int co = (((kc << 2) + lq) ^ lr) * 8;
        s16x8 bk = *(const s16x8*)(Ks + (sb * 16 + lr) * 128 + co);
#pragma unroll
        for (int mb = 0; mb < 2; ++mb)
          a[mb] = __builtin_amdgcn_mfma_f32_16x16x32_bf16(aq[mb][kc], bk, a[mb], 0, 0, 0);
      }
#pragma unroll
      for (int mb = 0; mb < 2; ++mb)
#pragma unroll
        for (int i = 0; i < 4; ++i) {
          const float u = exp2f(a[mb][i] * C_IN);
          const float r = __builtin_amdgcn_rcpf(u + 1.0f);
          p[mb][sb][i] = exp2f(fmaf(r, M_SCALE, M_BIAS));
        }
    }

    // mask only boundary tiles (wave-uniform branch)
    const bool interior = (s0 + 63 <= t0) && (s0 >= t0 + 127 - (WIN - 1));
    if (!interior) {
#pragma unroll
      for (int sb = 0; sb < 4; ++sb) {
        const int key = s0 + sb * 16 + lr;
#pragma unroll
        for (int mb = 0; mb < 2; ++mb)
#pragma unroll
          for (int i = 0; i < 4; ++i) {
            const int t = t0 + wave * 32 + mb * 16 + lq * 4 + i;
            if (key > t || key < t - (WIN - 1)) p[mb][sb][i] = 0.0f;
          }
      }
    }
#pragma unroll
    for (int mb = 0; mb < 2; ++mb)
#pragma unroll
      for (int sb = 0; sb < 4; ++sb)
#pragma unroll
        for (int i = 0; i < 4; ++i) lp[mb][i] += p[mb][sb][i];

    __syncthreads();  // (C) Ks QK-reads done before Ps overwrite
#pragma unroll
    for (int mb = 0; mb < 2; ++mb)
#pragma unroll
      for (int sb = 0; sb < 4; ++sb)
#pragma unroll
        for (int i = 0; i < 4; ++i) {
          const int row = mb * 16 + lq * 4 + i;
          const int cph = ((sb * 2 + (lr >> 3)) ^ (row & 7));
          Ps[row * 64 + cph * 8 + (lr & 7)] = f2b(p[mb][sb][i]);
        }
    __syncthreads();  // (D) Ps visible

    s16x8 ap[2][2];
#pragma unroll
    for (int mb = 0; mb < 2; ++mb)
#pragma unroll
      for (int kc = 0; kc < 2; ++kc)
        ap[mb][kc] = *(const s16x8*)(Ps + (mb * 16 + lr) * 64 +
                                     ((((kc << 2) + lq) ^ (lr & 7)) * 8));

#pragma unroll
    for (int hb = 0; hb < 8; ++hb) {
#pragma unroll
      for (int kc = 0; kc < 2; ++kc) {
        const int co = (((kc << 2) + lq) ^ (lr & 7)) * 8;
        s16x8 bv = *(const s16x8*)(Vt + (hb * 16 + lr) * 64 + co);
#pragma unroll
        for (int mb = 0; mb < 2; ++mb)
          oacc[mb][hb] = __builtin_amdgcn_mfma_f32_16x16x32_bf16(ap[mb][kc], bv, oacc[mb][hb], 0, 0, 0);
      }
    }
  }

  // l: reduce per-lane partials across the 16 lr-lanes
#pragma unroll
  for (int mb = 0; mb < 2; ++mb)
#pragma unroll
    for (int i = 0; i < 4; ++i) {
#pragma unroll
      for (int off = 1; off < 16; off <<= 1)
        lp[mb][i] += __shfl_xor(lp[mb][i], off, 64);
    }

#pragma unroll
  for (int mb = 0; mb < 2; ++mb)
#pragma unroll
    for (int i = 0; i < 4; ++i) {
      const int t = t0 + wave * 32 + mb * 16 + lq * 4 + i;
      const float inv = 1.0f / lp[mb][i];
      const size_t rowb = ((size_t)b * T_ + t) * (N_ * H_) + (size_t)n * H_;
#pragma unroll
      for (int hb = 0; hb < 8; ++hb)
        enc[rowb + hb * 16 + lr] = f2b(oacc[mb][hb][i] * inv);
    }
}

// ---------------------------------------------------------------------------
extern "C" void kernel_launch(void* const* d_in, const int* in_sizes, int n_in,
                              void* d_out, int out_size, void* d_ws, size_t ws_size,
                              hipStream_t stream) {
  const void* x     = d_in[0];  // (B,T,D)    fp32 (auto-detected; bf16 hedge)
  const void* w_qkv = d_in[1];  // (3,N,D,H)
  const void* w_out = d_in[2];  // (N,H,D)

  // workspace (88 MB peak, proven safe):
  //   [0,64)          flag
  //   A [64,+16MB)    xc        -> later vt (v transposed, 16MB)
  //   B [+16,+40MB)   wqkvT     -> later enc(16MB) + woutT(8MB)
  //   C [+40,+88MB)   qkv: q(16) k(16) v(16)
  char* wsb = (char*)d_ws;
  int* flag = (int*)wsb;
  const size_t MB = 1048576;
  unsigned short* xc    = (unsigned short*)(wsb + 64);
  unsigned short* wqkvT = (unsigned short*)(wsb + 64 + 16 * MB);
  unsigned short* qkv   = (unsigned short*)(wsb + 64 + 40 * MB);
  unsigned short* vt    = xc;                                        // alias
  unsigned short* enc   = wqkvT;                                     // alias
  unsigned short* woutT = (unsigned short*)(wsb + 64 + 32 * MB);     // alias
  unsigned short* k     = qkv + (size_t)B_ * N_ * T_ * H_;
  unsigned short* v     = qkv + 2 * (size_t)B_ * N_ * T_ * H_;

  detect_kernel<<<1, 256, 0, stream>>>((const unsigned short*)x, flag);
  convert_x_kernel<<<8192, 256, 0, stream>>>(x, xc, flag, B_ * T_ * D_ / 4);
  transpose_kernel<<<dim3(4, 64, 48), dim3(32, 8), 0, stream>>>(w_qkv, wqkvT, 2048, 128, flag);
  gemm128_kernel<<<dim3(32, 48), 256, 0, stream>>>(xc, wqkvT, qkv, 1, flag);
  rope_kernel<<<16384, 256, 0, stream>>>(k);  // K only; Q roped inside attn
  transpose_bf16_kernel<<<dim3(4, 64, 32), dim3(32, 8), 0, stream>>>(v, vt, 2048, 128);
  transpose_kernel<<<dim3(64, 64, 1), dim3(32, 8), 0, stream>>>(w_out, woutT, 2048, 2048, flag);
  attn_kernel<<<dim3(32, 16), 256, 0, stream>>>(qkv, vt, enc);
  gemm128_kernel<<<dim3(32, 16), 256, 0, stream>>>(enc, woutT, d_out, 0, flag);
}